// Round 9
// baseline (127.628 us; speedup 1.0000x reference)
//
#include <hip/hip_runtime.h>
#include <math.h>

#define VOX_N    256
#define NLINKS   8
#define NSPH     8

// Opaque single-rounded f32 ops (inline asm): pins rounding/association
// against any compiler contraction, independent of harness flags.
__device__ __forceinline__ float fmul_o(float a, float b) {
    float r;
    asm volatile("v_mul_f32 %0, %1, %2" : "=v"(r) : "v"(a), "v"(b));
    return r;
}
__device__ __forceinline__ float fadd_o(float a, float b) {
    float r;
    asm volatile("v_add_f32 %0, %1, %2" : "=v"(r) : "v"(a), "v"(b));
    return r;
}

// one thread per (b,h,l); 8 sphere gathers per thread; shfl-sum over l.
//
// NUMERICS CONTRACT (hard-won across R0-R7; do not "optimize"):
//  - Comparison is bf16-quantized on both sides (all errors exactly k/16,
//    threshold exactly 2% of bf16-exact 8.8125): ONLY voxel flips matter.
//  - All-f32 pipelines with true divide fail identically (0.1875) in every
//    association order (plain-asc / fma-asc / plain-desc) => the ref's
//    index transform is systematically shifted vs the correctly-rounded
//    f32 divide. f64 anywhere makes it worse (0.4375).
//  - Hypothesis (this round): ref uses reciprocal-multiply — XLA-style
//    div-by-const canonicalization: (q + 1.28f) * 100.0f, where
//    f32(1/0.01f) == exactly 100.0f — a systematic -2.2e-8 relative shift
//    vs true divide, association-invariant, matching the stable flip set.
//  - pts: plain f32 mul/add chain, DESCENDING j (numpy einsum unrolled-
//    tail order), then + pos; every op opaque-asm, rounds once.
//  - tail: max, +(-0.01f), clip[0,0.5], *4 (exact), butterfly l-sum
//    (== numpy n=8 pairwise tree), * weight.
__global__ __launch_bounds__(256) void voxel_cost_kernel(
    const float* __restrict__ pos,   // [B*H*L*3]
    const float* __restrict__ rot,   // [B*H*L*9]
    const float* __restrict__ cen,   // [L*S*3]
    const float* __restrict__ rad,   // [L*S]
    const float* __restrict__ sdf,   // [256^3]
    const float* __restrict__ wgt,   // [1]
    float* __restrict__ out,         // [B*H]
    int total)                       // B*H*L
{
    __shared__ float s_cen[NLINKS * NSPH * 3];
    __shared__ float s_rad[NLINKS * NSPH];

    const int t = threadIdx.x;
    if (t < NLINKS * NSPH * 3) s_cen[t] = cen[t];
    if (t < NLINKS * NSPH)     s_rad[t] = rad[t];
    __syncthreads();

    const int gid = blockIdx.x * 256 + t;
    if (gid >= total) return;
    const int l = gid & (NLINKS - 1);

    // per-thread rotation (row-major 3x3) and translation
    const size_t rbase = (size_t)gid * 9;
    const float r0 = rot[rbase + 0], r1 = rot[rbase + 1], r2 = rot[rbase + 2];
    const float r3 = rot[rbase + 3], r4 = rot[rbase + 4], r5 = rot[rbase + 5];
    const float r6 = rot[rbase + 6], r7 = rot[rbase + 7], r8 = rot[rbase + 8];
    const size_t pbase = (size_t)gid * 3;
    const float p0 = pos[pbase + 0], p1 = pos[pbase + 1], p2 = pos[pbase + 2];

    float m = -3.402823466e38f;
    #pragma unroll
    for (int s = 0; s < NSPH; ++s) {
        const int cs = (l * NSPH + s) * 3;
        const float c0 = s_cen[cs + 0];
        const float c1 = s_cen[cs + 1];
        const float c2 = s_cen[cs + 2];
        // DESCENDING-j plain chain: ((r2*c2 + r1*c1) + r0*c0) + p
        const float q0 = fadd_o(fadd_o(fadd_o(fmul_o(r2, c2), fmul_o(r1, c1)), fmul_o(r0, c0)), p0);
        const float q1 = fadd_o(fadd_o(fadd_o(fmul_o(r5, c2), fmul_o(r4, c1)), fmul_o(r3, c0)), p1);
        const float q2 = fadd_o(fadd_o(fadd_o(fmul_o(r8, c2), fmul_o(r7, c1)), fmul_o(r6, c0)), p2);
        // voxel index: floor((q + 1.28f) * 100.0f) — reciprocal-multiply
        // (NOT divide), opaque ops; clip to [0,255]
        const int ix = min(max((int)floorf(fmul_o(fadd_o(q0, 1.28f), 100.0f)), 0), VOX_N - 1);
        const int iy = min(max((int)floorf(fmul_o(fadd_o(q1, 1.28f), 100.0f)), 0), VOX_N - 1);
        const int iz = min(max((int)floorf(fmul_o(fadd_o(q2, 1.28f), 100.0f)), 0), VOX_N - 1);
        const float g = sdf[(((ix << 8) + iy) << 8) + iz];
        const float pen = fadd_o(s_rad[l * NSPH + s], -g);
        m = fmaxf(m, pen);
    }

    // res + DIST_THRESHOLD, clip to [0, 0.5], / 0.25 (exact *4)
    float res = fadd_o(m, -0.01f);
    res = fminf(fmaxf(res, 0.0f), 0.5f) * 4.0f;

    // sum over l: 8 consecutive lanes share (b,h); butterfly tree equals
    // numpy n=8 pairwise sum ((a0+a1)+(a2+a3))+((a4+a5)+(a6+a7))
    res = fadd_o(res, __shfl_xor(res, 1, 64));
    res = fadd_o(res, __shfl_xor(res, 2, 64));
    res = fadd_o(res, __shfl_xor(res, 4, 64));

    if (l == 0) out[gid >> 3] = fmul_o(wgt[0], res);
}

extern "C" void kernel_launch(void* const* d_in, const int* in_sizes, int n_in,
                              void* d_out, int out_size, void* d_ws, size_t ws_size,
                              hipStream_t stream) {
    const float* pos = (const float*)d_in[0];  // link_pos_seq [B,H,L,3]
    const float* rot = (const float*)d_in[1];  // link_rot_seq [B,H,L,3,3]
    const float* cen = (const float*)d_in[2];  // sphere_centers [L,S,3]
    const float* rad = (const float*)d_in[3];  // sphere_radii [L,S]
    const float* sdf = (const float*)d_in[4];  // sdf_grid [256,256,256]
    const float* wgt = (const float*)d_in[5];  // weight scalar
    float* out = (float*)d_out;                // [B,H]

    const int total = in_sizes[0] / 3;         // B*H*L = 262144
    const int blocks = (total + 255) / 256;
    hipLaunchKernelGGL(voxel_cost_kernel, dim3(blocks), dim3(256), 0, stream,
                       pos, rot, cen, rad, sdf, wgt, out, total);
}

// Round 10
// 127.263 us; speedup vs baseline: 1.0029x; 1.0029x over previous
//
#include <hip/hip_runtime.h>
#include <math.h>

#define VOX_N    256
#define NLINKS   8
#define NSPH     8

// Opaque single-rounded f32 ops (inline asm, NON-volatile): pins the exact
// instruction/rounding but lets the scheduler reorder by data deps only —
// volatile would force program-order between ALL asm statements, which
// serialized the 8 gathers behind each iteration's pen/max chain in R8.
__device__ __forceinline__ float fmul_o(float a, float b) {
    float r;
    asm("v_mul_f32 %0, %1, %2" : "=v"(r) : "v"(a), "v"(b));
    return r;
}
__device__ __forceinline__ float fadd_o(float a, float b) {
    float r;
    asm("v_add_f32 %0, %1, %2" : "=v"(r) : "v"(a), "v"(b));
    return r;
}

// one thread per (b,h,l); 8 sphere gathers per thread; shfl-sum over l.
//
// NUMERICS CONTRACT (hard-won across R0-R8; verified absmax == 0.0):
//  - pts: plain f32 mul/add chain, DESCENDING j:
//      q = ((r2*c2 + r1*c1) + r0*c0) + p,  every op rounds once (no FMA).
//  - voxel: floor((q + 1.28f) * 100.0f) — RECIPROCAL-MULTIPLY, not divide
//    (f32(1/0.01f) == exactly 100.0f; true divide FAILS at absmax 0.1875).
//    f64 anywhere fails worse (0.4375). Comparison is bf16-quantized, only
//    voxel flips are visible — these two choices are the whole ballgame.
//  - tail: max (exact-assoc, any order), +(-0.01f), clip[0,0.5], *4
//    (exact), butterfly l-sum (== numpy n=8 pairwise tree), * weight.
__global__ __launch_bounds__(256) void voxel_cost_kernel(
    const float* __restrict__ pos,   // [B*H*L*3]
    const float* __restrict__ rot,   // [B*H*L*9]
    const float* __restrict__ cen,   // [L*S*3]
    const float* __restrict__ rad,   // [L*S]
    const float* __restrict__ sdf,   // [256^3]
    const float* __restrict__ wgt,   // [1]
    float* __restrict__ out,         // [B*H]
    int total)                       // B*H*L
{
    __shared__ float s_cen[NLINKS * NSPH * 3];
    __shared__ float s_rad[NLINKS * NSPH];

    const int t = threadIdx.x;
    if (t < NLINKS * NSPH * 3) s_cen[t] = cen[t];
    if (t < NLINKS * NSPH)     s_rad[t] = rad[t];
    __syncthreads();

    const int gid = blockIdx.x * 256 + t;
    if (gid >= total) return;
    const int l = gid & (NLINKS - 1);

    // per-thread rotation (row-major 3x3) and translation
    const size_t rbase = (size_t)gid * 9;
    const float r0 = rot[rbase + 0], r1 = rot[rbase + 1], r2 = rot[rbase + 2];
    const float r3 = rot[rbase + 3], r4 = rot[rbase + 4], r5 = rot[rbase + 5];
    const float r6 = rot[rbase + 6], r7 = rot[rbase + 7], r8 = rot[rbase + 8];
    const size_t pbase = (size_t)gid * 3;
    const float p0 = pos[pbase + 0], p1 = pos[pbase + 1], p2 = pos[pbase + 2];

    // Phase 1: compute all 24 voxel indices, issue all 8 independent
    // gathers (memory-level parallelism: one latency, not eight).
    float g[NSPH];
    #pragma unroll
    for (int s = 0; s < NSPH; ++s) {
        const int cs = (l * NSPH + s) * 3;
        const float c0 = s_cen[cs + 0];
        const float c1 = s_cen[cs + 1];
        const float c2 = s_cen[cs + 2];
        // DESCENDING-j plain chain: ((r2*c2 + r1*c1) + r0*c0) + p
        const float q0 = fadd_o(fadd_o(fadd_o(fmul_o(r2, c2), fmul_o(r1, c1)), fmul_o(r0, c0)), p0);
        const float q1 = fadd_o(fadd_o(fadd_o(fmul_o(r5, c2), fmul_o(r4, c1)), fmul_o(r3, c0)), p1);
        const float q2 = fadd_o(fadd_o(fadd_o(fmul_o(r8, c2), fmul_o(r7, c1)), fmul_o(r6, c0)), p2);
        // voxel index: floor((q + 1.28f) * 100.0f), clip to [0,255]
        const int ix = min(max((int)floorf(fmul_o(fadd_o(q0, 1.28f), 100.0f)), 0), VOX_N - 1);
        const int iy = min(max((int)floorf(fmul_o(fadd_o(q1, 1.28f), 100.0f)), 0), VOX_N - 1);
        const int iz = min(max((int)floorf(fmul_o(fadd_o(q2, 1.28f), 100.0f)), 0), VOX_N - 1);
        g[s] = sdf[(((ix << 8) + iy) << 8) + iz];
    }

    // Phase 2: combine. pen = rad - g; max over spheres (exact-assoc).
    float m = -3.402823466e38f;
    #pragma unroll
    for (int s = 0; s < NSPH; ++s) {
        const float pen = fadd_o(s_rad[l * NSPH + s], -g[s]);
        m = fmaxf(m, pen);
    }

    // res + DIST_THRESHOLD, clip to [0, 0.5], / 0.25 (exact *4)
    float res = fadd_o(m, -0.01f);
    res = fminf(fmaxf(res, 0.0f), 0.5f) * 4.0f;

    // sum over l: 8 consecutive lanes share (b,h); butterfly tree equals
    // numpy n=8 pairwise sum ((a0+a1)+(a2+a3))+((a4+a5)+(a6+a7))
    res = fadd_o(res, __shfl_xor(res, 1, 64));
    res = fadd_o(res, __shfl_xor(res, 2, 64));
    res = fadd_o(res, __shfl_xor(res, 4, 64));

    if (l == 0) out[gid >> 3] = fmul_o(wgt[0], res);
}

extern "C" void kernel_launch(void* const* d_in, const int* in_sizes, int n_in,
                              void* d_out, int out_size, void* d_ws, size_t ws_size,
                              hipStream_t stream) {
    const float* pos = (const float*)d_in[0];  // link_pos_seq [B,H,L,3]
    const float* rot = (const float*)d_in[1];  // link_rot_seq [B,H,L,3,3]
    const float* cen = (const float*)d_in[2];  // sphere_centers [L,S,3]
    const float* rad = (const float*)d_in[3];  // sphere_radii [L,S]
    const float* sdf = (const float*)d_in[4];  // sdf_grid [256,256,256]
    const float* wgt = (const float*)d_in[5];  // weight scalar
    float* out = (float*)d_out;                // [B,H]

    const int total = in_sizes[0] / 3;         // B*H*L = 262144
    const int blocks = (total + 255) / 256;
    hipLaunchKernelGGL(voxel_cost_kernel, dim3(blocks), dim3(256), 0, stream,
                       pos, rot, cen, rad, sdf, wgt, out, total);
}